// Round 5
// baseline (191.453 us; speedup 1.0000x reference)
//
#include <hip/hip_runtime.h>

#define BB 8
#define SS 4096
#define EE 256
#define CH 64          // chunks per batch
#define RW 64          // rows per chunk
#define NB1 (BB * CH)  // 512 sum-x blocks

// Workspace layout (floats). All partials deterministically written; the
// per-batch completion counters are zeroed by kA each replay (ws is poisoned
// 0xAA before every timed launch).
#define WS_SXP 0                          // [B][CH][E] chunk partial sums of x
#define WS_YP  (BB * CH * EE)             // [B][CH][E] chunk partial sums of w*x
#define WS_WP  (2 * BB * CH * EE)         // [B][CH]    chunk partial sums of w
#define WS_MT  (WS_WP + BB * CH)          // [E][E] MT[e][t] = (Wk^T Wq)[t][e]
#define WS_G   (WS_MT + EE * EE)          // [E] Wk^T bq
#define WS_H   (WS_G + EE)                // [E] Wq^T bk
#define WS_D0  (WS_H + EE)                // [1] bq . bk
#define WS_CNT (WS_D0 + 1)                // [B] int completion counters

// Node 1: weight prep (MT, g, h, d0), x chunk sums (sxp), counter zeroing.
__global__ __launch_bounds__(256) void kA(
    const float* __restrict__ x, const float* __restrict__ Wq,
    const float* __restrict__ bq, const float* __restrict__ Wk,
    const float* __restrict__ bk, const int* __restrict__ lengths,
    float* __restrict__ sxp, float* __restrict__ MT, float* __restrict__ g,
    float* __restrict__ h, float* __restrict__ d0, int* __restrict__ cnt)
{
    const int r = blockIdx.x, tid = threadIdx.x, wid = tid >> 6, lane = tid & 63;
    if (r < NB1) {
        // sxp[b][chunk][e] = sum over chunk's valid rows of x[b,s,e]
        const int b = r >> 6, chunk = r & (CH - 1);
        const int len = lengths[b];
        const int base = chunk * RW;
        if (base >= len) return;              // block-uniform; consumers skip
        const float4* xb = (const float4*)(x + (size_t)b * SS * EE);
        float4 acc = make_float4(0.f, 0.f, 0.f, 0.f);
        for (int rr = wid; rr < RW; rr += 4) {
            const int row = base + rr;        // wave-uniform predicate
            if (row < len) {
                float4 xv = xb[(size_t)row * (EE / 4) + lane];
                acc.x += xv.x; acc.y += xv.y; acc.z += xv.z; acc.w += xv.w;
            }
        }
        __shared__ float ysh[4][EE];
        ((float4*)ysh[wid])[lane] = acc;
        __syncthreads();
        sxp[((size_t)b * CH + chunk) * EE + tid] =
            ysh[0][tid] + ysh[1][tid] + ysh[2][tid] + ysh[3][tid];
    } else if (r < NB1 + EE) {
        // MT[e][t] = sum_f Wq[f][e] * Wk[f][t]   (coalesced Wk reads)
        const int e = r - NB1;
        __shared__ float col[EE];
        col[tid] = Wq[tid * EE + e];          // one strided load per thread
        __syncthreads();
        float acc = 0.f;
        #pragma unroll 8
        for (int f = 0; f < EE; ++f) acc += col[f] * Wk[f * EE + tid];
        MT[e * EE + tid] = acc;
    } else if (r == NB1 + EE) {
        // g[t] = sum_f Wk[f][t] * bq[f]; zero counters
        __shared__ float bs[EE];
        bs[tid] = bq[tid];
        __syncthreads();
        float acc = 0.f;
        #pragma unroll 8
        for (int f = 0; f < EE; ++f) acc += Wk[f * EE + tid] * bs[f];
        g[tid] = acc;
        if (tid < BB) cnt[tid] = 0;
    } else {
        // h[e] = sum_f Wq[f][e] * bk[f]; d0 = bq . bk
        __shared__ float bks[EE], bqs[EE];
        bks[tid] = bk[tid]; bqs[tid] = bq[tid];
        __syncthreads();
        float acc = 0.f;
        #pragma unroll 8
        for (int f = 0; f < EE; ++f) acc += Wq[f * EE + tid] * bks[f];
        h[tid] = acc;
        float p = bqs[tid] * bks[tid];
        #pragma unroll
        for (int m = 32; m; m >>= 1) p += __shfl_xor(p, m, 64);
        __shared__ float red[4];
        if (lane == 0) red[wid] = p;
        __syncthreads();
        if (tid == 0) d0[0] = red[0] + red[1] + red[2] + red[3];
    }
}

// Node 2: per block — rebuild sx,u,c; chunk pass (w_s = u.x_s + c, accumulate
// w_s x_s and w_s); per-batch last-finishing block does the Wv epilogue.
__global__ __launch_bounds__(256) void kB(
    const float* __restrict__ x, const float* __restrict__ Wv,
    const float* __restrict__ bv, const int* __restrict__ lengths,
    const float* __restrict__ sxp, const float* __restrict__ MT,
    const float* __restrict__ g, const float* __restrict__ h,
    const float* __restrict__ d0, float* __restrict__ yp,
    float* __restrict__ wp, int* __restrict__ cnt, float* __restrict__ out)
{
    const int chunk = blockIdx.x, b = blockIdx.y;
    const int tid = threadIdx.x, wid = tid >> 6, lane = tid & 63;
    const int len = lengths[b];
    const int nch = (len + RW - 1) / RW;
    const int base = chunk * RW;

    __shared__ float sxs[EE];
    __shared__ float ush[EE];
    __shared__ float ysh[4][EE];
    __shared__ float red[4];
    __shared__ float csh;
    __shared__ int flag;

    if (base < len) {                          // block-uniform
        // sx = sum of valid chunk partials (coalesced across tid)
        float s = 0.f;
        for (int ch = 0; ch < nch; ++ch)
            s += sxp[((size_t)b * CH + ch) * EE + tid];
        sxs[tid] = s;
        __syncthreads();
        const float lenf = (float)len;
        // u[t] = sum_e MT[e][t]*sx[e] + len*g[t]  (thread-per-output, coalesced)
        float ua = 0.f;
        #pragma unroll 8
        for (int e = 0; e < EE; ++e) ua += MT[e * EE + tid] * sxs[e];
        ush[tid] = ua + lenf * g[tid];
        // c = h.sx + len*d0
        float pc = h[tid] * sxs[tid];
        #pragma unroll
        for (int m = 32; m; m >>= 1) pc += __shfl_xor(pc, m, 64);
        if (lane == 0) red[wid] = pc;
        __syncthreads();
        if (tid == 0) csh = red[0] + red[1] + red[2] + red[3] + lenf * d0[0];
        __syncthreads();
        const float4 uv = ((const float4*)ush)[lane];
        const float cb = csh;
        // chunk pass over RW rows, 16 rows per wave
        const float4* xb = (const float4*)(x + (size_t)b * SS * EE);
        float4 yacc = make_float4(0.f, 0.f, 0.f, 0.f);
        float Wacc = 0.f;
        for (int rr = wid; rr < RW; rr += 4) {
            const int row = base + rr;         // wave-uniform predicate
            if (row < len) {
                float4 xv = xb[(size_t)row * (EE / 4) + lane];
                float p = uv.x * xv.x + uv.y * xv.y + uv.z * xv.z + uv.w * xv.w;
                #pragma unroll
                for (int m = 1; m < 64; m <<= 1) p += __shfl_xor(p, m, 64);
                p += cb;                       // w_s on all lanes
                yacc.x += p * xv.x; yacc.y += p * xv.y;
                yacc.z += p * xv.z; yacc.w += p * xv.w;
                Wacc += p;
            }
        }
        __syncthreads();                       // red reuse below
        ((float4*)ysh[wid])[lane] = yacc;
        if (lane == 0) red[wid] = Wacc;
        __syncthreads();
        yp[((size_t)b * CH + chunk) * EE + tid] =
            ysh[0][tid] + ysh[1][tid] + ysh[2][tid] + ysh[3][tid];
        if (tid == 0) wp[b * CH + chunk] = red[0] + red[1] + red[2] + red[3];
    }

    // completion ticket (all blocks, including empty ones)
    __threadfence();
    __syncthreads();
    if (tid == 0) flag = (atomicAdd(&cnt[b], 1) == CH - 1) ? 1 : 0;
    __syncthreads();
    if (flag) {                                // block-uniform
        __threadfence();                       // acquire other blocks' yp/wp
        float yv = 0.f;
        for (int ch = 0; ch < nch; ++ch)
            yv += yp[((size_t)b * CH + ch) * EE + tid];
        sxs[tid] = yv;                         // reuse as y
        float wv = (tid < nch) ? wp[b * CH + tid] : 0.f;   // nch <= 64
        #pragma unroll
        for (int m = 32; m; m >>= 1) wv += __shfl_xor(wv, m, 64);
        if (lane == 0) red[wid] = wv;
        __syncthreads();
        const float Wb = red[0] + red[1] + red[2] + red[3];
        const float4 yv4 = ((const float4*)sxs)[lane];
        // out[f] = (Wv[f,:].y + Wb*bv[f]) / S ; wave-per-output, 64 rows/wave
        for (int j = 0; j < 64; ++j) {
            const int f = wid * 64 + j;
            const float4 wr = ((const float4*)(Wv + f * EE))[lane];
            float p = wr.x * yv4.x + wr.y * yv4.y + wr.z * yv4.z + wr.w * yv4.w;
            #pragma unroll
            for (int m = 1; m < 64; m <<= 1) p += __shfl_xor(p, m, 64);
            if (lane == 0) out[b * EE + f] = (p + Wb * bv[f]) * (1.0f / SS);
        }
    }
}

extern "C" void kernel_launch(void* const* d_in, const int* in_sizes, int n_in,
                              void* d_out, int out_size, void* d_ws, size_t ws_size,
                              hipStream_t stream) {
    const float* x  = (const float*)d_in[0];
    const float* Wq = (const float*)d_in[1];
    const float* bq = (const float*)d_in[2];
    const float* Wk = (const float*)d_in[3];
    const float* bk = (const float*)d_in[4];
    const float* Wv = (const float*)d_in[5];
    const float* bv = (const float*)d_in[6];
    const int* lengths = (const int*)d_in[7];
    float* out = (float*)d_out;
    float* ws = (float*)d_ws;

    float* sxp = ws + WS_SXP;
    float* yp  = ws + WS_YP;
    float* wp  = ws + WS_WP;
    float* MT  = ws + WS_MT;
    float* g   = ws + WS_G;
    float* h   = ws + WS_H;
    float* d0  = ws + WS_D0;
    int*   cnt = (int*)(ws + WS_CNT);

    kA<<<NB1 + EE + 2, 256, 0, stream>>>(x, Wq, bq, Wk, bk, lengths,
                                         sxp, MT, g, h, d0, cnt);
    kB<<<dim3(CH, BB), 256, 0, stream>>>(x, Wv, bv, lengths, sxp, MT, g, h,
                                         d0, yp, wp, cnt, out);
}

// Round 6
// 185.703 us; speedup vs baseline: 1.0310x; 1.0310x over previous
//
#include <hip/hip_runtime.h>

#define BB 8
#define SS 4096
#define EE 256
#define CH 64          // chunks per batch
#define RW 64          // rows per chunk
#define NB1 (BB * CH)  // 512 chunk-sum blocks

// Workspace (floats), all deterministically written each launch:
//   sxp : [B][CH][E]  per-chunk partial sums of x
//   M   : [E][E]      M[t][e] = (Wk^T Wq)[t][e]  (row-major, row = output t)
//   g   : [E]         Wk^T bq
//   h   : [E]         Wq^T bk
//   d0  : [1]         bq . bk
#define WS_SXP 0
#define WS_M   (BB * CH * EE)
#define WS_G   (WS_M + EE * EE)
#define WS_H   (WS_G + EE)
#define WS_D0  (WS_H + EE)

// Node 1: x chunk sums + weight prep + zero out. Independent roles by blockIdx.
__global__ __launch_bounds__(256) void kA(
    const float* __restrict__ x, const float* __restrict__ Wq,
    const float* __restrict__ bq, const float* __restrict__ Wk,
    const float* __restrict__ bk, const int* __restrict__ lengths,
    float* __restrict__ sxp, float* __restrict__ M, float* __restrict__ g,
    float* __restrict__ h, float* __restrict__ d0, float* __restrict__ out)
{
    const int bid = blockIdx.x, tid = threadIdx.x, wid = tid >> 6, lane = tid & 63;
    if (bid < NB1) {
        // sxp[b][chunk][e] = sum of this chunk's valid rows of x
        const int b = bid >> 6, chunk = bid & (CH - 1);
        const int len = lengths[b];
        const int base = chunk * RW;
        if (base >= len) return;              // block-uniform; consumers skip
        const float4* xb = (const float4*)(x + (size_t)b * SS * EE);
        float4 acc = make_float4(0.f, 0.f, 0.f, 0.f);
        for (int rr = wid; rr < RW; rr += 4) {
            const int row = base + rr;        // wave-uniform predicate
            if (row < len) {
                float4 xv = xb[(size_t)row * (EE / 4) + lane];
                acc.x += xv.x; acc.y += xv.y; acc.z += xv.z; acc.w += xv.w;
            }
        }
        __shared__ float ysh[4][EE];
        ((float4*)ysh[wid])[lane] = acc;
        __syncthreads();
        sxp[((size_t)b * CH + chunk) * EE + tid] =
            ysh[0][tid] + ysh[1][tid] + ysh[2][tid] + ysh[3][tid];
    } else if (bid < NB1 + EE) {
        // M[row][t] = sum_f Wk[f][row] * Wq[f][t]  (coalesced Wq reads)
        const int row = bid - NB1;
        __shared__ float col[EE];
        col[tid] = Wk[tid * EE + row];        // one strided load per thread
        __syncthreads();
        float acc = 0.f;
        #pragma unroll 8
        for (int f = 0; f < EE; ++f) acc += col[f] * Wq[f * EE + tid];
        M[row * EE + tid] = acc;
    } else if (bid == NB1 + EE) {
        // g[t] = sum_f Wk[f][t] * bq[f]; zero out[] (poisoned each replay)
        __shared__ float bs[EE];
        bs[tid] = bq[tid];
        __syncthreads();
        float acc = 0.f;
        #pragma unroll 8
        for (int f = 0; f < EE; ++f) acc += Wk[f * EE + tid] * bs[f];
        g[tid] = acc;
        #pragma unroll
        for (int k = 0; k < BB; ++k) out[k * EE + tid] = 0.f;
    } else {
        // h[e] = sum_f Wq[f][e] * bk[f]; d0 = bq . bk
        __shared__ float bks[EE], bqs[EE];
        bks[tid] = bk[tid]; bqs[tid] = bq[tid];
        __syncthreads();
        float acc = 0.f;
        #pragma unroll 8
        for (int f = 0; f < EE; ++f) acc += Wq[f * EE + tid] * bks[f];
        h[tid] = acc;
        float p = bqs[tid] * bks[tid];
        #pragma unroll
        for (int m = 32; m; m >>= 1) p += __shfl_xor(p, m, 64);
        __shared__ float red[4];
        if (lane == 0) red[wid] = p;
        __syncthreads();
        if (tid == 0) d0[0] = red[0] + red[1] + red[2] + red[3];
    }
}

// Node 2: fully independent per chunk-block (no fences, no tickets):
// rebuild sx,u,c from L2-resident partials; chunk pass; per-chunk epilogue
// contribution atomically added into out (linearity of the Wv epilogue).
__global__ __launch_bounds__(256) void kC(
    const float* __restrict__ x, const float* __restrict__ Wv,
    const float* __restrict__ bv, const int* __restrict__ lengths,
    const float* __restrict__ sxp, const float* __restrict__ M,
    const float* __restrict__ g, const float* __restrict__ h,
    const float* __restrict__ d0, float* __restrict__ out)
{
    const int chunk = blockIdx.x, b = blockIdx.y;
    const int tid = threadIdx.x, wid = tid >> 6, lane = tid & 63;
    const int len = lengths[b];
    const int base = chunk * RW;
    if (base >= len) return;                   // block-uniform; adds nothing
    const int nch = (len + RW - 1) / RW;

    __shared__ float sxs[EE];                  // sx, later reused as y_chunk
    __shared__ float ush[EE];
    __shared__ float gsh[EE];
    __shared__ float ysh[4][EE];
    __shared__ float red[4];
    __shared__ float csh;

    // sx = sum of valid chunk partials (coalesced)
    float s = 0.f;
    for (int ch = 0; ch < nch; ++ch)
        s += sxp[((size_t)b * CH + ch) * EE + tid];
    sxs[tid] = s;
    gsh[tid] = g[tid];
    __syncthreads();
    const float lenf = (float)len;
    const float4 sxv = ((const float4*)sxs)[lane];
    // u[t] = M[t,:].sx + len*g[t]; wave-per-output, 64 independent row reads
    #pragma unroll 4
    for (int j = 0; j < 64; ++j) {
        const int t = wid * 64 + j;
        const float4 mr = ((const float4*)(M + t * EE))[lane];   // 1KB row
        float p = mr.x * sxv.x + mr.y * sxv.y + mr.z * sxv.z + mr.w * sxv.w;
        #pragma unroll
        for (int m = 1; m < 64; m <<= 1) p += __shfl_xor(p, m, 64);
        if (lane == 0) ush[t] = p + lenf * gsh[t];
    }
    // c = h.sx + len*d0
    float pc = h[tid] * sxs[tid];
    #pragma unroll
    for (int m = 32; m; m >>= 1) pc += __shfl_xor(pc, m, 64);
    if (lane == 0) red[wid] = pc;
    __syncthreads();
    if (tid == 0) csh = red[0] + red[1] + red[2] + red[3] + lenf * d0[0];
    __syncthreads();
    const float4 uv = ((const float4*)ush)[lane];
    const float cb = csh;

    // chunk pass: w_s = u.x_s + c; accumulate w_s*x_s and w_s
    const float4* xb = (const float4*)(x + (size_t)b * SS * EE);
    float4 yacc = make_float4(0.f, 0.f, 0.f, 0.f);
    float Wacc = 0.f;
    for (int rr = wid; rr < RW; rr += 4) {
        const int row = base + rr;             // wave-uniform predicate
        if (row < len) {
            float4 xv = xb[(size_t)row * (EE / 4) + lane];
            float p = uv.x * xv.x + uv.y * xv.y + uv.z * xv.z + uv.w * xv.w;
            #pragma unroll
            for (int m = 1; m < 64; m <<= 1) p += __shfl_xor(p, m, 64);
            p += cb;                           // w_s on all lanes
            yacc.x += p * xv.x; yacc.y += p * xv.y;
            yacc.z += p * xv.z; yacc.w += p * xv.w;
            Wacc += p;
        }
    }
    __syncthreads();                           // red/sxs reuse below
    ((float4*)ysh[wid])[lane] = yacc;
    if (lane == 0) red[wid] = Wacc;
    __syncthreads();
    sxs[tid] = ysh[0][tid] + ysh[1][tid] + ysh[2][tid] + ysh[3][tid]; // y_chunk
    __syncthreads();
    const float Wb = red[0] + red[1] + red[2] + red[3];
    const float4 yv4 = ((const float4*)sxs)[lane];
    const float inv = 1.0f / SS;
    // per-chunk epilogue: out[b] += (Wv . y_chunk + Wb*bv)/S
    #pragma unroll 4
    for (int j = 0; j < 64; ++j) {
        const int f = wid * 64 + j;
        const float4 wr = ((const float4*)(Wv + f * EE))[lane];  // 1KB row
        float p = wr.x * yv4.x + wr.y * yv4.y + wr.z * yv4.z + wr.w * yv4.w;
        #pragma unroll
        for (int m = 1; m < 64; m <<= 1) p += __shfl_xor(p, m, 64);
        if (lane == 0) atomicAdd(&out[b * EE + f], (p + Wb * bv[f]) * inv);
    }
}

extern "C" void kernel_launch(void* const* d_in, const int* in_sizes, int n_in,
                              void* d_out, int out_size, void* d_ws, size_t ws_size,
                              hipStream_t stream) {
    const float* x  = (const float*)d_in[0];
    const float* Wq = (const float*)d_in[1];
    const float* bq = (const float*)d_in[2];
    const float* Wk = (const float*)d_in[3];
    const float* bk = (const float*)d_in[4];
    const float* Wv = (const float*)d_in[5];
    const float* bv = (const float*)d_in[6];
    const int* lengths = (const int*)d_in[7];
    float* out = (float*)d_out;
    float* ws = (float*)d_ws;

    float* sxp = ws + WS_SXP;
    float* M   = ws + WS_M;
    float* g   = ws + WS_G;
    float* h   = ws + WS_H;
    float* d0  = ws + WS_D0;

    kA<<<NB1 + EE + 2, 256, 0, stream>>>(x, Wq, bq, Wk, bk, lengths,
                                         sxp, M, g, h, d0, out);
    kC<<<dim3(CH, BB), 256, 0, stream>>>(x, Wv, bv, lengths, sxp, M, g, h,
                                         d0, out);
}

// Round 7
// 140.892 us; speedup vs baseline: 1.3589x; 1.3181x over previous
//
#include <hip/hip_runtime.h>

#define BB 8
#define SS 4096
#define EE 256
#define CH1 64         // sxp chunks per batch (kA)
#define RW1 64         // rows per sxp chunk
#define CH2 128        // stream chunks per batch (kC)
#define RW2 32         // rows per stream chunk
#define NB1 (BB * CH1) // 512 chunk-sum blocks

// Workspace (floats):
#define WS_SXP  0                          // [B][CH1][E] chunk partial sums of x
#define WS_MT   (BB * CH1 * EE)            // [E][E] MT[e][t] = sum_f Wk[f][t]Wq[f][e]
#define WS_WVT  (WS_MT + EE * EE)          // [E][E] WvT[e][f] = Wv[f][e]
#define WS_G    (WS_WVT + EE * EE)         // [E] Wk^T bq
#define WS_H    (WS_G + EE)                // [E] Wq^T bk
#define WS_D0   (WS_H + EE)                // [1] bq.bk
#define WS_U    (WS_D0 + 1)                // [B][E] u vectors
#define WS_CV   (WS_U + BB * EE)           // [B] c scalars
#define WS_Y    (WS_CV + BB)               // [B][E] y accumulators (atomic)
#define WS_WSUM (WS_Y + BB * EE)           // [B] W accumulators (atomic)

// Node 1: sxp chunk sums, MT, WvT, g, h, d0, zero y/Wsum. Roles by blockIdx.
__global__ __launch_bounds__(256) void kA(
    const float* __restrict__ x, const float* __restrict__ Wq,
    const float* __restrict__ bq, const float* __restrict__ Wk,
    const float* __restrict__ bk, const float* __restrict__ Wv,
    const int* __restrict__ lengths,
    float* __restrict__ sxp, float* __restrict__ MT, float* __restrict__ WvT,
    float* __restrict__ g, float* __restrict__ h, float* __restrict__ d0,
    float* __restrict__ y, float* __restrict__ Wsum)
{
    const int bid = blockIdx.x, tid = threadIdx.x, wid = tid >> 6, lane = tid & 63;
    if (bid < NB1) {
        // sxp[b][chunk][e] = sum of chunk's valid rows of x
        const int b = bid >> 6, chunk = bid & (CH1 - 1);
        const int len = lengths[b];
        const int base = chunk * RW1;
        if (base >= len) return;              // block-uniform; kB skips these
        const float4* xb = (const float4*)(x + (size_t)b * SS * EE);
        float4 acc = make_float4(0.f, 0.f, 0.f, 0.f);
        for (int rr = wid; rr < RW1; rr += 4) {
            const int row = base + rr;        // wave-uniform predicate
            if (row < len) {
                float4 xv = xb[(size_t)row * (EE / 4) + lane];
                acc.x += xv.x; acc.y += xv.y; acc.z += xv.z; acc.w += xv.w;
            }
        }
        __shared__ float ysh[4][EE];
        ((float4*)ysh[wid])[lane] = acc;
        __syncthreads();
        sxp[((size_t)b * CH1 + chunk) * EE + tid] =
            ysh[0][tid] + ysh[1][tid] + ysh[2][tid] + ysh[3][tid];
    } else if (bid < NB1 + EE) {
        // MT[e][t] = sum_f Wq[f][e] * Wk[f][t]  (coalesced Wk reads)
        const int e = bid - NB1;
        __shared__ float wqcol[EE];
        wqcol[tid] = Wq[tid * EE + e];        // one strided load per thread
        __syncthreads();
        float acc = 0.f;
        #pragma unroll 8
        for (int f = 0; f < EE; ++f) acc += wqcol[f] * Wk[f * EE + tid];
        MT[e * EE + tid] = acc;
    } else if (bid < NB1 + 2 * EE) {
        // WvT[e][f] = Wv[f][e]  (strided read, coalesced write)
        const int e = bid - NB1 - EE;
        WvT[e * EE + tid] = Wv[tid * EE + e];
    } else if (bid == NB1 + 2 * EE) {
        // g[t] = sum_f Wk[f][t] * bq[f]; zero y and Wsum
        __shared__ float bs[EE];
        bs[tid] = bq[tid];
        __syncthreads();
        float acc = 0.f;
        #pragma unroll 8
        for (int f = 0; f < EE; ++f) acc += Wk[f * EE + tid] * bs[f];
        g[tid] = acc;
        #pragma unroll
        for (int k = 0; k < BB; ++k) y[k * EE + tid] = 0.f;
        if (tid < BB) Wsum[tid] = 0.f;
    } else {
        // h[e] = sum_f Wq[f][e] * bk[f]; d0 = bq.bk
        __shared__ float bks[EE], bqs[EE];
        bks[tid] = bk[tid]; bqs[tid] = bq[tid];
        __syncthreads();
        float acc = 0.f;
        #pragma unroll 8
        for (int f = 0; f < EE; ++f) acc += Wq[f * EE + tid] * bks[f];
        h[tid] = acc;
        float p = bqs[tid] * bks[tid];
        #pragma unroll
        for (int m = 32; m; m >>= 1) p += __shfl_xor(p, m, 64);
        __shared__ float red[4];
        if (lane == 0) red[wid] = p;
        __syncthreads();
        if (tid == 0) d0[0] = red[0] + red[1] + red[2] + red[3];
    }
}

// Node 2 (8 blocks): sx = sum sxp chunks; u = MT^T-matvec + len*g; c = h.sx+len*d0
__global__ __launch_bounds__(256) void kB(
    const int* __restrict__ lengths, const float* __restrict__ sxp,
    const float* __restrict__ MT, const float* __restrict__ g,
    const float* __restrict__ h, const float* __restrict__ d0,
    float* __restrict__ u, float* __restrict__ cvec)
{
    const int b = blockIdx.x, tid = threadIdx.x, wid = tid >> 6, lane = tid & 63;
    const int len = lengths[b];
    const int nch = (len + RW1 - 1) / RW1;
    __shared__ float sxs[EE];
    float s = 0.f;
    for (int ch = 0; ch < nch; ++ch)
        s += sxp[((size_t)b * CH1 + ch) * EE + tid];   // coalesced
    sxs[tid] = s;
    __syncthreads();
    const float lenf = (float)len;
    // u[t] = sum_e MT[e][t] * sx[e] + len*g[t]  (thread-per-output, coalesced)
    float ua = 0.f;
    #pragma unroll 8
    for (int e = 0; e < EE; ++e) ua += MT[e * EE + tid] * sxs[e];
    u[b * EE + tid] = ua + lenf * g[tid];
    // c = h.sx + len*d0
    float pc = h[tid] * sxs[tid];
    #pragma unroll
    for (int m = 32; m; m >>= 1) pc += __shfl_xor(pc, m, 64);
    __shared__ float red[4];
    if (lane == 0) red[wid] = pc;
    __syncthreads();
    if (tid == 0) cvec[b] = red[0] + red[1] + red[2] + red[3] + lenf * d0[0];
}

// Node 3 (128x8 blocks): stage chunk to LDS + row dots (shfl), then
// shuffle-free broadcast-FMA y-pass; atomicAdd into y[b], Wsum[b].
__global__ __launch_bounds__(256) void kC(
    const float* __restrict__ x, const int* __restrict__ lengths,
    const float* __restrict__ u, const float* __restrict__ cvec,
    float* __restrict__ y, float* __restrict__ Wsum)
{
    const int chunk = blockIdx.x, b = blockIdx.y;
    const int tid = threadIdx.x, wid = tid >> 6, lane = tid & 63;
    const int len = lengths[b];
    const int base = chunk * RW2;
    if (base >= len) return;                   // block-uniform
    const int nvalid = min(RW2, len - base);

    __shared__ float Xs[RW2][EE];              // 32 KB tile
    __shared__ float wl[RW2];
    __shared__ float ush[EE];
    ush[tid] = u[b * EE + tid];
    __syncthreads();
    const float4 uv = ((const float4*)ush)[lane];
    const float cb = cvec[b];

    const float4* xb = (const float4*)(x + (size_t)b * SS * EE);
    for (int rr = wid; rr < RW2; rr += 4) {    // 8 rows per wave
        const int row = base + rr;             // wave-uniform predicate
        if (row < len) {
            float4 xv = xb[(size_t)row * (EE / 4) + lane];
            ((float4*)Xs[rr])[lane] = xv;      // conflict-free write
            float p = uv.x * xv.x + uv.y * xv.y + uv.z * xv.z + uv.w * xv.w;
            #pragma unroll
            for (int m = 1; m < 64; m <<= 1) p += __shfl_xor(p, m, 64);
            if (lane == 0) wl[rr] = p + cb;    // w_s
        }
    }
    __syncthreads();
    // y-pass: thread t accumulates sum_s w_s * X[s][t]  (broadcast + coalesced)
    float yacc = 0.f;
    for (int s = 0; s < nvalid; ++s)
        yacc += wl[s] * Xs[s][tid];
    atomicAdd(&y[b * EE + tid], yacc);
    // W = sum_s w_s : wave 0 only, one shfl chain
    if (wid == 0) {
        float wv = (lane < nvalid) ? wl[lane] : 0.f;   // nvalid <= 32 <= 64
        #pragma unroll
        for (int m = 1; m < 32; m <<= 1) wv += __shfl_xor(wv, m, 64);
        if (lane == 0) atomicAdd(&Wsum[b], wv);
    }
}

// Node 4 (8 blocks): out[b][f] = (sum_e WvT[e][f] y[e] + Wsum[b]*bv[f]) / S
__global__ __launch_bounds__(256) void kD(
    const float* __restrict__ WvT, const float* __restrict__ bv,
    const float* __restrict__ y, const float* __restrict__ Wsum,
    float* __restrict__ out)
{
    const int b = blockIdx.x, tid = threadIdx.x;
    __shared__ float ysh[EE];
    ysh[tid] = y[b * EE + tid];
    __syncthreads();
    const float Wb = Wsum[b];
    float acc = 0.f;
    #pragma unroll 8
    for (int e = 0; e < EE; ++e) acc += WvT[e * EE + tid] * ysh[e];  // coalesced
    out[b * EE + tid] = (acc + Wb * bv[tid]) * (1.0f / SS);
}

extern "C" void kernel_launch(void* const* d_in, const int* in_sizes, int n_in,
                              void* d_out, int out_size, void* d_ws, size_t ws_size,
                              hipStream_t stream) {
    const float* x  = (const float*)d_in[0];
    const float* Wq = (const float*)d_in[1];
    const float* bq = (const float*)d_in[2];
    const float* Wk = (const float*)d_in[3];
    const float* bk = (const float*)d_in[4];
    const float* Wv = (const float*)d_in[5];
    const float* bv = (const float*)d_in[6];
    const int* lengths = (const int*)d_in[7];
    float* out = (float*)d_out;
    float* ws = (float*)d_ws;

    float* sxp  = ws + WS_SXP;
    float* MT   = ws + WS_MT;
    float* WvT  = ws + WS_WVT;
    float* g    = ws + WS_G;
    float* h    = ws + WS_H;
    float* d0   = ws + WS_D0;
    float* u    = ws + WS_U;
    float* cvec = ws + WS_CV;
    float* y    = ws + WS_Y;
    float* Wsum = ws + WS_WSUM;

    kA<<<NB1 + 2 * EE + 2, 256, 0, stream>>>(x, Wq, bq, Wk, bk, Wv, lengths,
                                             sxp, MT, WvT, g, h, d0, y, Wsum);
    kB<<<BB, 256, 0, stream>>>(lengths, sxp, MT, g, h, d0, u, cvec);
    kC<<<dim3(CH2, BB), 256, 0, stream>>>(x, lengths, u, cvec, y, Wsum);
    kD<<<BB, 256, 0, stream>>>(WvT, bv, y, Wsum, out);
}